// Round 5
// baseline (1549.080 us; speedup 1.0000x reference)
//
#include <hip/hip_runtime.h>
#include <stdint.h>
#include <math.h>

// Problem constants
#define N_FEAT 16384   // B*H*W = 16*32*32
#define K_CODES 8192
#define C_DIM 256

typedef _Float16 f16;
typedef f16 f16x8 __attribute__((ext_vector_type(8)));
typedef f16 f16x4 __attribute__((ext_vector_type(4)));
typedef float f32x4 __attribute__((ext_vector_type(4)));

// Workspace layout (float offsets)
#define OFF_ZH      ((size_t)0)            // f16[16384][256] -> 2097152 float slots
#define OFF_ZL      ((size_t)2097152)      // f16[16384][256]
#define OFF_EH      ((size_t)4194304)      // f16[8192][256] -> 1048576
#define OFF_EL      ((size_t)5242880)
#define OFF_ZN      ((size_t)6291456)      // f32[16384]
#define OFF_EN      ((size_t)6307840)      // f32[8192]
#define OFF_ROWBEST ((size_t)6316032)      // u64[16384] -> 32768 floats
#define OFF_COLBEST ((size_t)6348800)      // u64[8192]  -> 16384 floats
#define OFF_TOKEN   ((size_t)6365184)      // int[16384]
#define OFF_HIST    ((size_t)6381568)      // int[8192]
#define OFF_SCAL    ((size_t)6389760)      // [0]=sqsum, [1]=plog, [2]=util(int)

// Output layout (float offsets into d_out)
#define OUT_ZQ    ((size_t)0)          // 4194304
#define OUT_LOSS  ((size_t)4194304)
#define OUT_QERR  ((size_t)4194305)
#define OUT_UTIL  ((size_t)4194306)
#define OUT_PERP  ((size_t)4194307)
#define OUT_NEWE  ((size_t)4194308)    // 2097152
#define OUT_NEWP  ((size_t)6291460)    // 8192

#define LSTR 40   // LDS row stride in halfs (80 B: 16B-aligned, 2-way-free reads)

__device__ __forceinline__ unsigned order_f32(float f) {
    unsigned u = __float_as_uint(f);
    return (u & 0x80000000u) ? ~u : (u | 0x80000000u);
}
__device__ __forceinline__ unsigned long long pack_min_key(float f, unsigned idx) {
    return ((unsigned long long)order_f32(f) << 32) | idx;   // min-d, tie: small idx
}
__device__ __forceinline__ unsigned long long pack_max_key(float f, unsigned idx) {
    return ((unsigned long long)(~order_f32(f)) << 32) | idx; // max-d, tie: small idx
}

// ---------------- transpose z (B,C,H,W) -> split-fp16 zh/zl in (N,C) ----------------
__global__ void zprep_kernel(const float* __restrict__ z, f16* __restrict__ zh,
                             f16* __restrict__ zl) {
    __shared__ float tile[32][33];
    const int b = blockIdx.z;
    const int c0 = blockIdx.y * 32;
    const int hw0 = blockIdx.x * 32;
    const int tx = threadIdx.x, ty = threadIdx.y; // 32 x 8
#pragma unroll
    for (int i = 0; i < 4; i++) {
        int c = c0 + ty + i * 8;
        tile[ty + i * 8][tx] = z[(size_t)(b * 256 + c) * 1024 + hw0 + tx];
    }
    __syncthreads();
#pragma unroll
    for (int i = 0; i < 4; i++) {
        int hw = hw0 + ty + i * 8;
        float v = tile[tx][ty + i * 8];
        f16 h = (f16)v;
        f16 l = (f16)((v - (float)h) * 2048.0f);
        size_t o = (size_t)(b * 1024 + hw) * 256 + c0 + tx;
        zh[o] = h;
        zl[o] = l;
    }
}

// ---------------- embedding -> split-fp16 (scaled by 16384) ----------------
__global__ void eprep_kernel(const float* __restrict__ emb, f16* __restrict__ eh,
                             f16* __restrict__ el) {
    int i = blockIdx.x * 256 + threadIdx.x;  // per 4 elements
    float4 v = *(const float4*)(emb + (size_t)i * 4);
    f16x4 h, l;
    float s[4] = {v.x, v.y, v.z, v.w};
#pragma unroll
    for (int q = 0; q < 4; q++) {
        float es = s[q] * 16384.0f;
        f16 hh = (f16)es;
        h[q] = hh;
        l[q] = (f16)((es - (float)hh) * 2048.0f);
    }
    *(f16x4*)(eh + (size_t)i * 4) = h;
    *(f16x4*)(el + (size_t)i * 4) = l;
}

// ---------------- zn from z (strided over c, coalesced over hw) ----------------
__global__ void zn_kernel(const float* __restrict__ z, float* __restrict__ zn) {
    int i = blockIdx.x * 256 + threadIdx.x;  // 64 blocks
    int b = i >> 10, hw = i & 1023;
    const float* p = z + (size_t)b * 262144 + hw;
    float s = 0.0f;
#pragma unroll 8
    for (int c = 0; c < 256; c++) { float v = p[(size_t)c * 1024]; s = fmaf(v, v, s); }
    zn[i] = s;
}

// ---------------- en from emb rows ----------------
__global__ void en_kernel(const float* __restrict__ emb, float* __restrict__ en) {
    int gid = blockIdx.x * 4 + (threadIdx.x >> 6);  // 2048 blocks
    int lane = threadIdx.x & 63;
    float4 v = *(const float4*)(emb + (size_t)gid * 256 + lane * 4);
    float s = v.x * v.x + v.y * v.y + v.z * v.z + v.w * v.w;
#pragma unroll
    for (int m = 32; m >= 1; m >>= 1) s += __shfl_xor(s, m);
    if (lane == 0) en[gid] = s;
}

// ---------------- MFMA distance + fused argmin/argmax ----------------
// 128x128 tile, 4 waves (2x2), K-step 32. dot*16384 = accA + accB/2048.
__launch_bounds__(256, 2)
__global__ void dist_mfma_kernel(const f16* __restrict__ zh, const f16* __restrict__ zl,
                                 const f16* __restrict__ eh, const f16* __restrict__ el,
                                 const float* __restrict__ zn, const float* __restrict__ en,
                                 unsigned long long* __restrict__ rowbest,
                                 unsigned long long* __restrict__ colbest) {
    __shared__ f16 sZH[128 * LSTR];
    __shared__ f16 sZL[128 * LSTR];
    __shared__ f16 sEH[128 * LSTR];
    __shared__ f16 sEL[128 * LSTR];

    const int tid = threadIdx.x;
    const int m0 = blockIdx.y * 128;
    const int k0 = blockIdx.x * 128;
    const int srow = tid >> 1, shalf = (tid & 1) * 16;
    const int wave = tid >> 6, lane = tid & 63;
    const int wr = wave >> 1, wc = wave & 1;
    const int lg = lane >> 4, l15 = lane & 15;

    f32x4 accA[4][4];
    f32x4 accB[4][4];
#pragma unroll
    for (int i = 0; i < 4; i++)
#pragma unroll
        for (int j = 0; j < 4; j++) {
            accA[i][j] = (f32x4){0.f, 0.f, 0.f, 0.f};
            accB[i][j] = (f32x4){0.f, 0.f, 0.f, 0.f};
        }

    const size_t gaBase = (size_t)(m0 + srow) * 256 + shalf;
    const size_t gbBase = (size_t)(k0 + srow) * 256 + shalf;
    const int so = srow * LSTR + shalf;

    for (int cc = 0; cc < 256; cc += 32) {
        f16x8 a0 = *(const f16x8*)(zh + gaBase + cc);
        f16x8 a1 = *(const f16x8*)(zh + gaBase + cc + 8);
        f16x8 c0 = *(const f16x8*)(zl + gaBase + cc);
        f16x8 c1 = *(const f16x8*)(zl + gaBase + cc + 8);
        f16x8 b0 = *(const f16x8*)(eh + gbBase + cc);
        f16x8 b1 = *(const f16x8*)(eh + gbBase + cc + 8);
        f16x8 d0 = *(const f16x8*)(el + gbBase + cc);
        f16x8 d1 = *(const f16x8*)(el + gbBase + cc + 8);
        __syncthreads();   // previous compute done before overwrite
        *(f16x8*)(sZH + so) = a0; *(f16x8*)(sZH + so + 8) = a1;
        *(f16x8*)(sZL + so) = c0; *(f16x8*)(sZL + so + 8) = c1;
        *(f16x8*)(sEH + so) = b0; *(f16x8*)(sEH + so + 8) = b1;
        *(f16x8*)(sEL + so) = d0; *(f16x8*)(sEL + so + 8) = d1;
        __syncthreads();

        f16x8 ah[4], al[4];
#pragma unroll
        for (int t = 0; t < 4; t++) {
            int ra = (wr * 64 + t * 16 + l15) * LSTR + lg * 8;
            ah[t] = *(const f16x8*)(sZH + ra);
            al[t] = *(const f16x8*)(sZL + ra);
        }
#pragma unroll
        for (int j = 0; j < 4; j++) {
            int rb = (wc * 64 + j * 16 + l15) * LSTR + lg * 8;
            f16x8 bh = *(const f16x8*)(sEH + rb);
            f16x8 bl = *(const f16x8*)(sEL + rb);
#pragma unroll
            for (int i = 0; i < 4; i++) {
                accA[i][j] = __builtin_amdgcn_mfma_f32_16x16x32_f16(ah[i], bh, accA[i][j], 0, 0, 0);
                accB[i][j] = __builtin_amdgcn_mfma_f32_16x16x32_f16(ah[i], bl, accB[i][j], 0, 0, 0);
                accB[i][j] = __builtin_amdgcn_mfma_f32_16x16x32_f16(al[i], bh, accB[i][j], 0, 0, 0);
            }
        }
    }

    // ---- epilogue ----
    const float invK = 1.0f / 16384.0f;
    const float inv2048 = 1.0f / 2048.0f;
    float enl[4], znl[4][4];
#pragma unroll
    for (int j = 0; j < 4; j++) enl[j] = en[k0 + wc * 64 + j * 16 + l15];
#pragma unroll
    for (int i = 0; i < 4; i++)
#pragma unroll
        for (int r = 0; r < 4; r++) znl[i][r] = zn[m0 + wr * 64 + i * 16 + lg * 4 + r];

    // per-row argmin over this block's 128 cols (wave covers 64 cols)
#pragma unroll
    for (int i = 0; i < 4; i++)
#pragma unroll
        for (int r = 0; r < 4; r++) {
            float bv = 3.0e38f;
            int bk = 0;
#pragma unroll
            for (int j = 0; j < 4; j++) {
                float dot = (accA[i][j][r] + accB[i][j][r] * inv2048) * invK;
                float d = znl[i][r] + enl[j] - 2.0f * dot;
                int k = k0 + wc * 64 + j * 16 + l15;
                if (d < bv || (d == bv && k < bk)) { bv = d; bk = k; }
            }
#pragma unroll
            for (int m = 1; m < 16; m <<= 1) {
                float ov = __shfl_xor(bv, m);
                int oi = __shfl_xor(bk, m);
                if (ov < bv || (ov == bv && oi < bk)) { bv = ov; bk = oi; }
            }
            if (l15 == 0)
                atomicMin(&rowbest[m0 + wr * 64 + i * 16 + lg * 4 + r],
                          pack_min_key(bv, (unsigned)bk));
        }

    // per-col argmax over this block's 128 rows (wave covers 64 rows)
#pragma unroll
    for (int j = 0; j < 4; j++) {
        float cv = -3.0e38f;
        int cm = 0;
#pragma unroll
        for (int i = 0; i < 4; i++)
#pragma unroll
            for (int r = 0; r < 4; r++) {
                float dot = (accA[i][j][r] + accB[i][j][r] * inv2048) * invK;
                float d = znl[i][r] + enl[j] - 2.0f * dot;
                int mm = m0 + wr * 64 + i * 16 + lg * 4 + r;
                if (d > cv || (d == cv && mm < cm)) { cv = d; cm = mm; }
            }
#pragma unroll
        for (int m = 16; m < 64; m <<= 1) {
            float ov = __shfl_xor(cv, m);
            int oi = __shfl_xor(cm, m);
            if (ov > cv || (ov == cv && oi < cm)) { cv = ov; cm = oi; }
        }
        if (lane < 16)
            atomicMin(&colbest[k0 + wc * 64 + j * 16 + l15], pack_max_key(cv, (unsigned)cm));
    }
}

// ---------------- token decode + histogram ----------------
__global__ void token_kernel(const unsigned long long* __restrict__ rowbest,
                             int* __restrict__ token, int* __restrict__ hist) {
    int i = blockIdx.x * 256 + threadIdx.x;
    int t = (int)(rowbest[i] & 0xffffffffULL);
    token[i] = t;
    atomicAdd(&hist[t], 1);
}

// ---------------- z_q gather/write (B,C,H,W) + squared-error sum ----------------
__global__ void zq_kernel(const float* __restrict__ z, const float* __restrict__ emb,
                          const int* __restrict__ token, float* __restrict__ out0,
                          float* __restrict__ sqsum) {
    int t = blockIdx.x * 256 + threadIdx.x;
    int w = t & 31, h = (t >> 5) & 31, b = t >> 18;
    int c = (t >> 10) & 255;
    int i = b * 1024 + h * 32 + w;
    int tok = token[i];
    float v = emb[(size_t)tok * C_DIM + c];
    float zv = z[t];
    float d = v - zv;
    out0[t] = v;
    float s = d * d;
#pragma unroll
    for (int m = 32; m >= 1; m >>= 1) s += __shfl_xor(s, m);
    if ((threadIdx.x & 63) == 0) atomicAdd(sqsum, s);
}

// ---------------- per-code embedding update + perplexity/util partials ----------------
__global__ void embed_kernel(const float* __restrict__ z, const float* __restrict__ emb,
                             const float* __restrict__ prob, const int* __restrict__ hist,
                             const unsigned long long* __restrict__ colbest,
                             float* __restrict__ newe, float* __restrict__ newp,
                             float* __restrict__ plog, int* __restrict__ util) {
    int j = blockIdx.x;
    int tid = threadIdx.x; // 64
    int cnt = hist[j];
    float avg = (float)cnt * (1.0f / 16384.0f);
    float npb = prob[j] * 0.99f + avg * 0.01f;
    float decay = expf(-npb * 8192000.0f - 0.001f);   // npb*K*10/(1-DECAY)
    if (tid == 0) {
        newp[j] = npb;
        atomicAdd(plog, avg * logf(avg + 1e-10f));
        if (cnt > 0) atomicAdd(util, 1);
    }
    float4 e4 = *(const float4*)(emb + (size_t)j * C_DIM + tid * 4);
    float4 o = e4;
    if (decay > 0.0f) {
        int far = (int)(colbest[j] & 0xffffffffULL);
        int b = far >> 10, hw = far & 1023;
        const float* zp = z + (size_t)b * 262144 + hw;
        float om = 1.0f - decay;
        float zq[4];
#pragma unroll
        for (int q = 0; q < 4; q++) zq[q] = zp[(size_t)(tid * 4 + q) * 1024];
        o.x = e4.x * om + zq[0] * decay;
        o.y = e4.y * om + zq[1] * decay;
        o.z = e4.z * om + zq[2] * decay;
        o.w = e4.w * om + zq[3] * decay;
    }
    *(float4*)(newe + (size_t)j * C_DIM + tid * 4) = o;
}

// ---------------- scalar finalize ----------------
__global__ void final_kernel(const float* __restrict__ scal, const int* __restrict__ util,
                             float* __restrict__ out) {
    float sq = scal[0];
    out[OUT_LOSS] = 1.25f * sq / 4194304.0f;
    out[OUT_QERR] = sq / 16384.0f;
    out[OUT_UTIL] = (float)(*util) / 8192.0f;
    out[OUT_PERP] = expf(-scal[1]);
}

extern "C" void kernel_launch(void* const* d_in, const int* in_sizes, int n_in,
                              void* d_out, int out_size, void* d_ws, size_t ws_size,
                              hipStream_t stream) {
    const float* z = (const float*)d_in[0];
    const float* emb = (const float*)d_in[1];
    const float* prob = (const float*)d_in[2];
    float* out = (float*)d_out;
    float* ws = (float*)d_ws;

    f16* zh = (f16*)(ws + OFF_ZH);
    f16* zl = (f16*)(ws + OFF_ZL);
    f16* eh = (f16*)(ws + OFF_EH);
    f16* el = (f16*)(ws + OFF_EL);
    float* zn = ws + OFF_ZN;
    float* en = ws + OFF_EN;
    unsigned long long* rowbest = (unsigned long long*)(ws + OFF_ROWBEST);
    unsigned long long* colbest = (unsigned long long*)(ws + OFF_COLBEST);
    int* token = (int*)(ws + OFF_TOKEN);
    int* hist = (int*)(ws + OFF_HIST);
    float* scal = ws + OFF_SCAL;

    hipMemsetAsync(rowbest, 0xFF, (N_FEAT + K_CODES) * sizeof(unsigned long long), stream);
    hipMemsetAsync(hist, 0, K_CODES * sizeof(int) + 16, stream);

    zprep_kernel<<<dim3(32, 8, 16), dim3(32, 8), 0, stream>>>(z, zh, zl);
    eprep_kernel<<<K_CODES * C_DIM / 4 / 256, 256, 0, stream>>>(emb, eh, el);
    zn_kernel<<<N_FEAT / 256, 256, 0, stream>>>(z, zn);
    en_kernel<<<K_CODES / 4, 256, 0, stream>>>(emb, en);
    dist_mfma_kernel<<<dim3(K_CODES / 128, N_FEAT / 128), 256, 0, stream>>>(
        zh, zl, eh, el, zn, en, rowbest, colbest);
    token_kernel<<<N_FEAT / 256, 256, 0, stream>>>(rowbest, token, hist);
    zq_kernel<<<N_FEAT * C_DIM / 256, 256, 0, stream>>>(z, emb, token, out + OUT_ZQ, scal);
    embed_kernel<<<K_CODES, 64, 0, stream>>>(z, emb, prob, hist, colbest,
                                             out + OUT_NEWE, out + OUT_NEWP,
                                             scal + 1, (int*)(scal + 2));
    final_kernel<<<1, 1, 0, stream>>>(scal, (int*)(scal + 2), out);
}

// Round 6
// 563.568 us; speedup vs baseline: 2.7487x; 2.7487x over previous
//
#include <hip/hip_runtime.h>
#include <stdint.h>
#include <math.h>

// Problem constants
#define N_FEAT 16384   // B*H*W = 16*32*32
#define K_CODES 8192
#define C_DIM 256

typedef _Float16 f16;
typedef f16 f16x8 __attribute__((ext_vector_type(8)));
typedef f16 f16x4 __attribute__((ext_vector_type(4)));
typedef float f32x4 __attribute__((ext_vector_type(4)));

// Workspace layout (float offsets)
#define OFF_ZH      ((size_t)0)            // f16[16384][256] -> 2097152 float slots
#define OFF_ZL      ((size_t)2097152)      // f16[16384][256]
#define OFF_EH      ((size_t)4194304)      // f16[8192][256] -> 1048576
#define OFF_EL      ((size_t)5242880)
#define OFF_ZN      ((size_t)6291456)      // f32[16384]
#define OFF_EN      ((size_t)6307840)      // f32[8192]
#define OFF_ROWBEST ((size_t)6316032)      // u64[16384] -> 32768 floats (reused: see below)
#define OFF_COLBEST ((size_t)6348800)      // u64[8192]  -> 16384 floats
#define OFF_TOKEN   ((size_t)6365184)      // int[16384]
#define OFF_HIST    ((size_t)6381568)      // int[8192]
// After token_kernel, rowbest region is dead -> reuse for reduction partials:
#define OFF_PART    OFF_ROWBEST            // f32[16384] zq per-block partial sq-sums
#define OFF_PL      (OFF_ROWBEST + 16384)  // f32[8192] per-code plog contribution
#define OFF_UT      (OFF_ROWBEST + 24576)  // int[8192] per-code used flag

// Output layout (float offsets into d_out)
#define OUT_ZQ    ((size_t)0)          // 4194304
#define OUT_LOSS  ((size_t)4194304)
#define OUT_QERR  ((size_t)4194305)
#define OUT_UTIL  ((size_t)4194306)
#define OUT_PERP  ((size_t)4194307)
#define OUT_NEWE  ((size_t)4194308)    // 2097152
#define OUT_NEWP  ((size_t)6291460)    // 8192

#define LSTR 40   // LDS row stride in halfs (80 B: 16B-aligned, 2-way-free reads)

__device__ __forceinline__ unsigned order_f32(float f) {
    unsigned u = __float_as_uint(f);
    return (u & 0x80000000u) ? ~u : (u | 0x80000000u);
}
__device__ __forceinline__ unsigned long long pack_min_key(float f, unsigned idx) {
    return ((unsigned long long)order_f32(f) << 32) | idx;   // min-d, tie: small idx
}
__device__ __forceinline__ unsigned long long pack_max_key(float f, unsigned idx) {
    return ((unsigned long long)(~order_f32(f)) << 32) | idx; // max-d, tie: small idx
}

// ---------------- transpose z (B,C,H,W) -> split-fp16 zh/zl in (N,C) ----------------
__global__ void zprep_kernel(const float* __restrict__ z, f16* __restrict__ zh,
                             f16* __restrict__ zl) {
    __shared__ float tile[32][33];
    const int b = blockIdx.z;
    const int c0 = blockIdx.y * 32;
    const int hw0 = blockIdx.x * 32;
    const int tx = threadIdx.x, ty = threadIdx.y; // 32 x 8
#pragma unroll
    for (int i = 0; i < 4; i++) {
        int c = c0 + ty + i * 8;
        tile[ty + i * 8][tx] = z[(size_t)(b * 256 + c) * 1024 + hw0 + tx];
    }
    __syncthreads();
#pragma unroll
    for (int i = 0; i < 4; i++) {
        int hw = hw0 + ty + i * 8;
        float v = tile[tx][ty + i * 8];
        f16 h = (f16)v;
        f16 l = (f16)((v - (float)h) * 2048.0f);
        size_t o = (size_t)(b * 1024 + hw) * 256 + c0 + tx;
        zh[o] = h;
        zl[o] = l;
    }
}

// ---------------- embedding -> split-fp16 (scaled by 16384) ----------------
__global__ void eprep_kernel(const float* __restrict__ emb, f16* __restrict__ eh,
                             f16* __restrict__ el) {
    int i = blockIdx.x * 256 + threadIdx.x;  // per 4 elements
    float4 v = *(const float4*)(emb + (size_t)i * 4);
    f16x4 h, l;
    float s[4] = {v.x, v.y, v.z, v.w};
#pragma unroll
    for (int q = 0; q < 4; q++) {
        float es = s[q] * 16384.0f;
        f16 hh = (f16)es;
        h[q] = hh;
        l[q] = (f16)((es - (float)hh) * 2048.0f);
    }
    *(f16x4*)(eh + (size_t)i * 4) = h;
    *(f16x4*)(el + (size_t)i * 4) = l;
}

// ---------------- zn from z (strided over c, coalesced over hw) ----------------
__global__ void zn_kernel(const float* __restrict__ z, float* __restrict__ zn) {
    int i = blockIdx.x * 256 + threadIdx.x;  // 64 blocks
    int b = i >> 10, hw = i & 1023;
    const float* p = z + (size_t)b * 262144 + hw;
    float s = 0.0f;
#pragma unroll 8
    for (int c = 0; c < 256; c++) { float v = p[(size_t)c * 1024]; s = fmaf(v, v, s); }
    zn[i] = s;
}

// ---------------- en from emb rows ----------------
__global__ void en_kernel(const float* __restrict__ emb, float* __restrict__ en) {
    int gid = blockIdx.x * 4 + (threadIdx.x >> 6);  // 2048 blocks
    int lane = threadIdx.x & 63;
    float4 v = *(const float4*)(emb + (size_t)gid * 256 + lane * 4);
    float s = v.x * v.x + v.y * v.y + v.z * v.z + v.w * v.w;
#pragma unroll
    for (int m = 32; m >= 1; m >>= 1) s += __shfl_xor(s, m);
    if (lane == 0) en[gid] = s;
}

// ---------------- MFMA distance + fused argmin/argmax ----------------
// 128x128 tile, 4 waves (2x2), K-step 32. dot*16384 = accA + accB/2048.
__launch_bounds__(256, 2)
__global__ void dist_mfma_kernel(const f16* __restrict__ zh, const f16* __restrict__ zl,
                                 const f16* __restrict__ eh, const f16* __restrict__ el,
                                 const float* __restrict__ zn, const float* __restrict__ en,
                                 unsigned long long* __restrict__ rowbest,
                                 unsigned long long* __restrict__ colbest) {
    __shared__ f16 sZH[128 * LSTR];
    __shared__ f16 sZL[128 * LSTR];
    __shared__ f16 sEH[128 * LSTR];
    __shared__ f16 sEL[128 * LSTR];

    const int tid = threadIdx.x;
    const int m0 = blockIdx.y * 128;
    const int k0 = blockIdx.x * 128;
    const int srow = tid >> 1, shalf = (tid & 1) * 16;
    const int wave = tid >> 6, lane = tid & 63;
    const int wr = wave >> 1, wc = wave & 1;
    const int lg = lane >> 4, l15 = lane & 15;

    f32x4 accA[4][4];
    f32x4 accB[4][4];
#pragma unroll
    for (int i = 0; i < 4; i++)
#pragma unroll
        for (int j = 0; j < 4; j++) {
            accA[i][j] = (f32x4){0.f, 0.f, 0.f, 0.f};
            accB[i][j] = (f32x4){0.f, 0.f, 0.f, 0.f};
        }

    const size_t gaBase = (size_t)(m0 + srow) * 256 + shalf;
    const size_t gbBase = (size_t)(k0 + srow) * 256 + shalf;
    const int so = srow * LSTR + shalf;

    for (int cc = 0; cc < 256; cc += 32) {
        f16x8 a0 = *(const f16x8*)(zh + gaBase + cc);
        f16x8 a1 = *(const f16x8*)(zh + gaBase + cc + 8);
        f16x8 c0 = *(const f16x8*)(zl + gaBase + cc);
        f16x8 c1 = *(const f16x8*)(zl + gaBase + cc + 8);
        f16x8 b0 = *(const f16x8*)(eh + gbBase + cc);
        f16x8 b1 = *(const f16x8*)(eh + gbBase + cc + 8);
        f16x8 d0 = *(const f16x8*)(el + gbBase + cc);
        f16x8 d1 = *(const f16x8*)(el + gbBase + cc + 8);
        __syncthreads();   // previous compute done before overwrite
        *(f16x8*)(sZH + so) = a0; *(f16x8*)(sZH + so + 8) = a1;
        *(f16x8*)(sZL + so) = c0; *(f16x8*)(sZL + so + 8) = c1;
        *(f16x8*)(sEH + so) = b0; *(f16x8*)(sEH + so + 8) = b1;
        *(f16x8*)(sEL + so) = d0; *(f16x8*)(sEL + so + 8) = d1;
        __syncthreads();

        f16x8 ah[4], al[4];
#pragma unroll
        for (int t = 0; t < 4; t++) {
            int ra = (wr * 64 + t * 16 + l15) * LSTR + lg * 8;
            ah[t] = *(const f16x8*)(sZH + ra);
            al[t] = *(const f16x8*)(sZL + ra);
        }
#pragma unroll
        for (int j = 0; j < 4; j++) {
            int rb = (wc * 64 + j * 16 + l15) * LSTR + lg * 8;
            f16x8 bh = *(const f16x8*)(sEH + rb);
            f16x8 bl = *(const f16x8*)(sEL + rb);
#pragma unroll
            for (int i = 0; i < 4; i++) {
                accA[i][j] = __builtin_amdgcn_mfma_f32_16x16x32_f16(ah[i], bh, accA[i][j], 0, 0, 0);
                accB[i][j] = __builtin_amdgcn_mfma_f32_16x16x32_f16(ah[i], bl, accB[i][j], 0, 0, 0);
                accB[i][j] = __builtin_amdgcn_mfma_f32_16x16x32_f16(al[i], bh, accB[i][j], 0, 0, 0);
            }
        }
    }

    // ---- epilogue ----
    const float invK = 1.0f / 16384.0f;
    const float inv2048 = 1.0f / 2048.0f;
    float enl[4], znl[4][4];
#pragma unroll
    for (int j = 0; j < 4; j++) enl[j] = en[k0 + wc * 64 + j * 16 + l15];
#pragma unroll
    for (int i = 0; i < 4; i++)
#pragma unroll
        for (int r = 0; r < 4; r++) znl[i][r] = zn[m0 + wr * 64 + i * 16 + lg * 4 + r];

    // per-row argmin over this block's 128 cols (wave covers 64 cols)
#pragma unroll
    for (int i = 0; i < 4; i++)
#pragma unroll
        for (int r = 0; r < 4; r++) {
            float bv = 3.0e38f;
            int bk = 0;
#pragma unroll
            for (int j = 0; j < 4; j++) {
                float dot = (accA[i][j][r] + accB[i][j][r] * inv2048) * invK;
                float d = znl[i][r] + enl[j] - 2.0f * dot;
                int k = k0 + wc * 64 + j * 16 + l15;
                if (d < bv || (d == bv && k < bk)) { bv = d; bk = k; }
            }
#pragma unroll
            for (int m = 1; m < 16; m <<= 1) {
                float ov = __shfl_xor(bv, m);
                int oi = __shfl_xor(bk, m);
                if (ov < bv || (ov == bv && oi < bk)) { bv = ov; bk = oi; }
            }
            if (l15 == 0)
                atomicMin(&rowbest[m0 + wr * 64 + i * 16 + lg * 4 + r],
                          pack_min_key(bv, (unsigned)bk));
        }

    // per-col argmax over this block's 128 rows (wave covers 64 rows)
#pragma unroll
    for (int j = 0; j < 4; j++) {
        float cv = -3.0e38f;
        int cm = 0;
#pragma unroll
        for (int i = 0; i < 4; i++)
#pragma unroll
            for (int r = 0; r < 4; r++) {
                float dot = (accA[i][j][r] + accB[i][j][r] * inv2048) * invK;
                float d = znl[i][r] + enl[j] - 2.0f * dot;
                int mm = m0 + wr * 64 + i * 16 + lg * 4 + r;
                if (d > cv || (d == cv && mm < cm)) { cv = d; cm = mm; }
            }
#pragma unroll
        for (int m = 16; m < 64; m <<= 1) {
            float ov = __shfl_xor(cv, m);
            int oi = __shfl_xor(cm, m);
            if (ov > cv || (ov == cv && oi < cm)) { cv = ov; cm = oi; }
        }
        if (lane < 16)
            atomicMin(&colbest[k0 + wc * 64 + j * 16 + l15], pack_max_key(cv, (unsigned)cm));
    }
}

// ---------------- token decode + histogram ----------------
__global__ void token_kernel(const unsigned long long* __restrict__ rowbest,
                             int* __restrict__ token, int* __restrict__ hist) {
    int i = blockIdx.x * 256 + threadIdx.x;
    int t = (int)(rowbest[i] & 0xffffffffULL);
    token[i] = t;
    atomicAdd(&hist[t], 1);
}

// ---------------- z_q gather/write (B,C,H,W) + per-block sq-err partial ----------------
__global__ void zq_kernel(const float* __restrict__ z, const float* __restrict__ emb,
                          const int* __restrict__ token, float* __restrict__ out0,
                          float* __restrict__ partial) {
    __shared__ float ps[4];
    int t = blockIdx.x * 256 + threadIdx.x;
    int w = t & 31, h = (t >> 5) & 31, b = t >> 18;
    int c = (t >> 10) & 255;
    int i = b * 1024 + h * 32 + w;
    int tok = token[i];
    float v = emb[(size_t)tok * C_DIM + c];
    float zv = z[t];
    float d = v - zv;
    out0[t] = v;
    float s = d * d;
#pragma unroll
    for (int m = 32; m >= 1; m >>= 1) s += __shfl_xor(s, m);
    if ((threadIdx.x & 63) == 0) ps[threadIdx.x >> 6] = s;
    __syncthreads();
    if (threadIdx.x == 0) partial[blockIdx.x] = ps[0] + ps[1] + ps[2] + ps[3];
}

// ---------------- per-code embedding update + per-code plog/util (no atomics) -------
__global__ void embed_kernel(const float* __restrict__ z, const float* __restrict__ emb,
                             const float* __restrict__ prob, const int* __restrict__ hist,
                             const unsigned long long* __restrict__ colbest,
                             float* __restrict__ newe, float* __restrict__ newp,
                             float* __restrict__ pl, int* __restrict__ ut) {
    int j = blockIdx.x;
    int tid = threadIdx.x; // 64
    int cnt = hist[j];
    float avg = (float)cnt * (1.0f / 16384.0f);
    float npb = prob[j] * 0.99f + avg * 0.01f;
    float decay = expf(-npb * 8192000.0f - 0.001f);   // npb*K*10/(1-DECAY)
    if (tid == 0) {
        newp[j] = npb;
        pl[j] = avg * logf(avg + 1e-10f);
        ut[j] = (cnt > 0) ? 1 : 0;
    }
    float4 e4 = *(const float4*)(emb + (size_t)j * C_DIM + tid * 4);
    float4 o = e4;
    if (decay > 0.0f) {
        int far = (int)(colbest[j] & 0xffffffffULL);
        int b = far >> 10, hw = far & 1023;
        const float* zp = z + (size_t)b * 262144 + hw;
        float om = 1.0f - decay;
        float zq[4];
#pragma unroll
        for (int q = 0; q < 4; q++) zq[q] = zp[(size_t)(tid * 4 + q) * 1024];
        o.x = e4.x * om + zq[0] * decay;
        o.y = e4.y * om + zq[1] * decay;
        o.z = e4.z * om + zq[2] * decay;
        o.w = e4.w * om + zq[3] * decay;
    }
    *(float4*)(newe + (size_t)j * C_DIM + tid * 4) = o;
}

// ---------------- scalar finalize: reduce partials, write 4 scalars ----------------
__global__ void final_kernel(const float* __restrict__ partial, const float* __restrict__ pl,
                             const int* __restrict__ ut, float* __restrict__ out) {
    int tid = threadIdx.x;  // 256
    float sq = 0.0f, pg = 0.0f;
    int uc = 0;
    for (int i = tid; i < 16384; i += 256) sq += partial[i];
    for (int i = tid; i < 8192; i += 256) { pg += pl[i]; uc += ut[i]; }
    float ucf = (float)uc;
#pragma unroll
    for (int m = 32; m >= 1; m >>= 1) {
        sq += __shfl_xor(sq, m);
        pg += __shfl_xor(pg, m);
        ucf += __shfl_xor(ucf, m);
    }
    __shared__ float s1[4], s2[4], s3[4];
    if ((tid & 63) == 0) {
        int w = tid >> 6;
        s1[w] = sq; s2[w] = pg; s3[w] = ucf;
    }
    __syncthreads();
    if (tid == 0) {
        float tsq = s1[0] + s1[1] + s1[2] + s1[3];
        float tpg = s2[0] + s2[1] + s2[2] + s2[3];
        float tuc = s3[0] + s3[1] + s3[2] + s3[3];
        out[OUT_LOSS] = 1.25f * tsq / 4194304.0f;
        out[OUT_QERR] = tsq / 16384.0f;
        out[OUT_UTIL] = tuc / 8192.0f;
        out[OUT_PERP] = expf(-tpg);
    }
}

extern "C" void kernel_launch(void* const* d_in, const int* in_sizes, int n_in,
                              void* d_out, int out_size, void* d_ws, size_t ws_size,
                              hipStream_t stream) {
    const float* z = (const float*)d_in[0];
    const float* emb = (const float*)d_in[1];
    const float* prob = (const float*)d_in[2];
    float* out = (float*)d_out;
    float* ws = (float*)d_ws;

    f16* zh = (f16*)(ws + OFF_ZH);
    f16* zl = (f16*)(ws + OFF_ZL);
    f16* eh = (f16*)(ws + OFF_EH);
    f16* el = (f16*)(ws + OFF_EL);
    float* zn = ws + OFF_ZN;
    float* en = ws + OFF_EN;
    unsigned long long* rowbest = (unsigned long long*)(ws + OFF_ROWBEST);
    unsigned long long* colbest = (unsigned long long*)(ws + OFF_COLBEST);
    int* token = (int*)(ws + OFF_TOKEN);
    int* hist = (int*)(ws + OFF_HIST);
    float* part = ws + OFF_PART;   // aliases rowbest (dead after token_kernel)
    float* pl = ws + OFF_PL;
    int* ut = (int*)(ws + OFF_UT);

    hipMemsetAsync(rowbest, 0xFF, (N_FEAT + K_CODES) * sizeof(unsigned long long), stream);
    hipMemsetAsync(hist, 0, K_CODES * sizeof(int), stream);

    zprep_kernel<<<dim3(32, 8, 16), dim3(32, 8), 0, stream>>>(z, zh, zl);
    eprep_kernel<<<K_CODES * C_DIM / 4 / 256, 256, 0, stream>>>(emb, eh, el);
    zn_kernel<<<N_FEAT / 256, 256, 0, stream>>>(z, zn);
    en_kernel<<<K_CODES / 4, 256, 0, stream>>>(emb, en);
    dist_mfma_kernel<<<dim3(K_CODES / 128, N_FEAT / 128), 256, 0, stream>>>(
        zh, zl, eh, el, zn, en, rowbest, colbest);
    token_kernel<<<N_FEAT / 256, 256, 0, stream>>>(rowbest, token, hist);
    zq_kernel<<<N_FEAT * C_DIM / 256, 256, 0, stream>>>(z, emb, token, out + OUT_ZQ, part);
    embed_kernel<<<K_CODES, 64, 0, stream>>>(z, emb, prob, hist, colbest,
                                             out + OUT_NEWE, out + OUT_NEWP, pl, ut);
    final_kernel<<<1, 256, 0, stream>>>(part, pl, ut, out);
}

// Round 8
// 541.908 us; speedup vs baseline: 2.8586x; 1.0400x over previous
//
#include <hip/hip_runtime.h>
#include <stdint.h>
#include <math.h>

// Problem constants
#define N_FEAT 16384   // B*H*W = 16*32*32
#define K_CODES 8192
#define C_DIM 256

typedef _Float16 f16;
typedef f16 f16x8 __attribute__((ext_vector_type(8)));
typedef float f32x4 __attribute__((ext_vector_type(4)));

// Workspace layout (float offsets) — same 25.6 MB footprint as round 6
#define OFF_ZH      ((size_t)0)            // f16[16384][256]
#define OFF_ZLD     ((size_t)2097152)      // f16[16384][256]  zld = z - zh (unscaled)
#define OFF_EH      ((size_t)4194304)      // f16[8192][256]   eh  = f16(e*16384)
#define OFF_ELD     ((size_t)5242880)      // f16[8192][256]   eld = e*16384 - eh
#define OFF_ZN      ((size_t)6291456)      // f32[16384]
#define OFF_EN      ((size_t)6307840)      // f32[8192]
#define OFF_ROWBEST ((size_t)6316032)      // u64[16384]
#define OFF_COLBEST ((size_t)6348800)      // u64[8192]
#define OFF_TOKEN   ((size_t)6365184)      // int[16384]
#define OFF_HIST    ((size_t)6381568)      // int[8192]
// rowbest region dead after token_kernel -> reuse:
#define OFF_PART    OFF_ROWBEST            // f32[16384]
#define OFF_PL      (OFF_ROWBEST + 16384)  // f32[8192]
#define OFF_UT      (OFF_ROWBEST + 24576)  // int[8192]

// Output layout (float offsets into d_out)
#define OUT_ZQ    ((size_t)0)
#define OUT_LOSS  ((size_t)4194304)
#define OUT_QERR  ((size_t)4194305)
#define OUT_UTIL  ((size_t)4194306)
#define OUT_PERP  ((size_t)4194307)
#define OUT_NEWE  ((size_t)4194308)
#define OUT_NEWP  ((size_t)6291460)

__device__ __forceinline__ unsigned order_f32(float f) {
    unsigned u = __float_as_uint(f);
    return (u & 0x80000000u) ? ~u : (u | 0x80000000u);
}
__device__ __forceinline__ unsigned long long pack_min_key(float f, unsigned idx) {
    return ((unsigned long long)order_f32(f) << 32) | idx;
}
__device__ __forceinline__ unsigned long long pack_max_key(float f, unsigned idx) {
    return ((unsigned long long)(~order_f32(f)) << 32) | idx;
}

// async global->LDS, 16 B per lane (dest: wave-uniform base + lane*16)
__device__ __forceinline__ void gload16(const f16* g, f16* l) {
    __builtin_amdgcn_global_load_lds(
        (const __attribute__((address_space(1))) unsigned int*)(const void*)g,
        (__attribute__((address_space(3))) unsigned int*)(void*)l,
        16, 0, 0);
}

// ---------------- transpose z (B,C,H,W) -> split-f16 zh/zld in (N,C) ----------------
__global__ void zprep_kernel(const float* __restrict__ z, f16* __restrict__ zh,
                             f16* __restrict__ zld) {
    __shared__ float tile[32][33];
    const int b = blockIdx.z;
    const int c0 = blockIdx.y * 32;
    const int hw0 = blockIdx.x * 32;
    const int tx = threadIdx.x, ty = threadIdx.y; // 32 x 8
#pragma unroll
    for (int i = 0; i < 4; i++) {
        int c = c0 + ty + i * 8;
        tile[ty + i * 8][tx] = z[(size_t)(b * 256 + c) * 1024 + hw0 + tx];
    }
    __syncthreads();
#pragma unroll
    for (int i = 0; i < 4; i++) {
        int hw = hw0 + ty + i * 8;
        float v = tile[tx][ty + i * 8];
        f16 h = (f16)v;
        size_t o = (size_t)(b * 1024 + hw) * 256 + c0 + tx;
        zh[o] = h;
        zld[o] = (f16)(v - (float)h);
    }
}

// ---------------- embedding -> split-f16 (scaled by 16384) ----------------
__global__ void eprep_kernel(const float* __restrict__ emb, f16* __restrict__ eh,
                             f16* __restrict__ eld) {
    int i = blockIdx.x * 256 + threadIdx.x;  // per 4 elements
    float4 v = *(const float4*)(emb + (size_t)i * 4);
    float s[4] = {v.x, v.y, v.z, v.w};
    f16 h[4], l[4];
#pragma unroll
    for (int q = 0; q < 4; q++) {
        float es = s[q] * 16384.0f;
        h[q] = (f16)es;
        l[q] = (f16)(es - (float)h[q]);
    }
    *(uint64_t*)(eh + (size_t)i * 4) = *(uint64_t*)h;
    *(uint64_t*)(eld + (size_t)i * 4) = *(uint64_t*)l;
}

// ---------------- zn from z ----------------
__global__ void zn_kernel(const float* __restrict__ z, float* __restrict__ zn) {
    int i = blockIdx.x * 256 + threadIdx.x;
    int b = i >> 10, hw = i & 1023;
    const float* p = z + (size_t)b * 262144 + hw;
    float s = 0.0f;
#pragma unroll 8
    for (int c = 0; c < 256; c++) { float v = p[(size_t)c * 1024]; s = fmaf(v, v, s); }
    zn[i] = s;
}

// ---------------- en from emb rows ----------------
__global__ void en_kernel(const float* __restrict__ emb, float* __restrict__ en) {
    int gid = blockIdx.x * 4 + (threadIdx.x >> 6);
    int lane = threadIdx.x & 63;
    float4 v = *(const float4*)(emb + (size_t)gid * 256 + lane * 4);
    float s = v.x * v.x + v.y * v.y + v.z * v.z + v.w * v.w;
#pragma unroll
    for (int m = 32; m >= 1; m >>= 1) s += __shfl_xor(s, m);
    if (lane == 0) en[gid] = s;
}

// ---------------- MFMA distance + fused argmin/argmax (concat-K, single acc) --------
// 128x128 tile, 4 waves (2x2). K' = 768 in 24 chunks of 32:
//   c<8 : zh  x eh     (base product)
//   8-15: zld x eh     (A-side correction)
//   16+ : zh  x eld    (B-side correction)
// acc = dot * 16384;  d = zn + en - acc * (2/16384).
__launch_bounds__(256, 3)
__global__ void dist_mfma_kernel(const f16* __restrict__ zh, const f16* __restrict__ zld,
                                 const f16* __restrict__ eh, const f16* __restrict__ eld,
                                 const float* __restrict__ zn, const float* __restrict__ en,
                                 unsigned long long* __restrict__ rowbest,
                                 unsigned long long* __restrict__ colbest) {
    __shared__ f16 sA[2][4096];   // 128 rows x 32 halfs, granule-swizzled
    __shared__ f16 sB[2][4096];

    const int tid = threadIdx.x;
    const int m0 = blockIdx.y * 128;
    const int k0 = blockIdx.x * 128;
    const int wave = tid >> 6, lane = tid & 63;
    const int wr = wave >> 1, wc = wave & 1;
    const int lg = lane >> 4, l15 = lane & 15;

    // staging: granules G0 = tid, G1 = 256+tid; row = G>>2; src slot = (G&3) ^ ((G>>3)&3)
    const int G0 = tid, G1 = 256 + tid;
    const int aoff0 = (m0 + (G0 >> 2)) * 256 + (((G0 & 3) ^ ((G0 >> 3) & 3)) << 3);
    const int aoff1 = (m0 + (G1 >> 2)) * 256 + (((G1 & 3) ^ ((G1 >> 3) & 3)) << 3);
    const int boff0 = (k0 + (G0 >> 2)) * 256 + (((G0 & 3) ^ ((G0 >> 3) & 3)) << 3);
    const int boff1 = (k0 + (G1 >> 2)) * 256 + (((G1 & 3) ^ ((G1 >> 3) & 3)) << 3);

    // fragment read offsets (halfs): logical (row R, slot lg) lives at slot lg ^ ((R>>1)&3)
    int aro[4], bro[4];
#pragma unroll
    for (int t = 0; t < 4; t++) {
        int R = wr * 64 + t * 16 + l15;
        aro[t] = R * 32 + ((lg ^ ((R >> 1) & 3)) << 3);
        int RB = wc * 64 + t * 16 + l15;
        bro[t] = RB * 32 + ((lg ^ ((RB >> 1) & 3)) << 3);
    }

    f32x4 acc[4][4];
#pragma unroll
    for (int i = 0; i < 4; i++)
#pragma unroll
        for (int j = 0; j < 4; j++) acc[i][j] = (f32x4){0.f, 0.f, 0.f, 0.f};

    // prologue: stage chunk 0 into buf 0
    {
        const f16* As = zh; const f16* Bs = eh;
        gload16(As + aoff0, &sA[0][G0 * 8]);
        gload16(As + aoff1, &sA[0][G1 * 8]);
        gload16(Bs + boff0, &sB[0][G0 * 8]);
        gload16(Bs + boff1, &sB[0][G1 * 8]);
    }
    __syncthreads();

    int cur = 0;
    for (int c = 0; c < 24; ++c) {
        if (c < 23) {
            int cn = c + 1;
            int cp = cn >> 3, cc = (cn & 7) * 32;
            const f16* As = (cp == 1) ? zld : zh;
            const f16* Bs = (cp == 2) ? eld : eh;
            int nb = cur ^ 1;
            gload16(As + aoff0 + cc, &sA[nb][G0 * 8]);
            gload16(As + aoff1 + cc, &sA[nb][G1 * 8]);
            gload16(Bs + boff0 + cc, &sB[nb][G0 * 8]);
            gload16(Bs + boff1 + cc, &sB[nb][G1 * 8]);
        }
        f16x8 af[4];
#pragma unroll
        for (int t = 0; t < 4; t++) af[t] = *(const f16x8*)&sA[cur][aro[t]];
#pragma unroll
        for (int j = 0; j < 4; j++) {
            f16x8 bf = *(const f16x8*)&sB[cur][bro[j]];
#pragma unroll
            for (int i = 0; i < 4; i++)
                acc[i][j] = __builtin_amdgcn_mfma_f32_16x16x32_f16(af[i], bf, acc[i][j], 0, 0, 0);
        }
        __syncthreads();   // publish next buf; protect cur for overwrite
        cur ^= 1;
    }

    // ---- epilogue: d[i][j] = zn[m] + en[k] - acc * 2/16384 ----
    const float sc = 2.0f / 16384.0f;
    float enl[4], znl[4][4];
#pragma unroll
    for (int j = 0; j < 4; j++) enl[j] = en[k0 + wc * 64 + j * 16 + l15];
#pragma unroll
    for (int i = 0; i < 4; i++)
#pragma unroll
        for (int r = 0; r < 4; r++) znl[i][r] = zn[m0 + wr * 64 + i * 16 + lg * 4 + r];

    // per-row argmin over this block's 128 cols (wave covers 64 cols)
#pragma unroll
    for (int i = 0; i < 4; i++)
#pragma unroll
        for (int r = 0; r < 4; r++) {
            float bv = 3.0e38f;
            int bk = 0;
#pragma unroll
            for (int j = 0; j < 4; j++) {
                float d = znl[i][r] + enl[j] - acc[i][j][r] * sc;
                int k = k0 + wc * 64 + j * 16 + l15;
                if (d < bv || (d == bv && k < bk)) { bv = d; bk = k; }
            }
#pragma unroll
            for (int m = 1; m < 16; m <<= 1) {
                float ov = __shfl_xor(bv, m);
                int oi = __shfl_xor(bk, m);
                if (ov < bv || (ov == bv && oi < bk)) { bv = ov; bk = oi; }
            }
            if (l15 == 0)
                atomicMin(&rowbest[m0 + wr * 64 + i * 16 + lg * 4 + r],
                          pack_min_key(bv, (unsigned)bk));
        }

    // per-col argmax over this block's 128 rows (wave covers 64 rows)
#pragma unroll
    for (int j = 0; j < 4; j++) {
        float cv = -3.0e38f;
        int cm = 0;
#pragma unroll
        for (int i = 0; i < 4; i++)
#pragma unroll
            for (int r = 0; r < 4; r++) {
                float d = znl[i][r] + enl[j] - acc[i][j][r] * sc;
                int mm = m0 + wr * 64 + i * 16 + lg * 4 + r;
                if (d > cv || (d == cv && mm < cm)) { cv = d; cm = mm; }
            }
#pragma unroll
        for (int m = 16; m < 64; m <<= 1) {
            float ov = __shfl_xor(cv, m);
            int oi = __shfl_xor(cm, m);
            if (ov > cv || (ov == cv && oi < cm)) { cv = ov; cm = oi; }
        }
        if (lane < 16)
            atomicMin(&colbest[k0 + wc * 64 + j * 16 + l15], pack_max_key(cv, (unsigned)cm));
    }
}

// ---------------- token decode + histogram ----------------
__global__ void token_kernel(const unsigned long long* __restrict__ rowbest,
                             int* __restrict__ token, int* __restrict__ hist) {
    int i = blockIdx.x * 256 + threadIdx.x;
    int t = (int)(rowbest[i] & 0xffffffffULL);
    token[i] = t;
    atomicAdd(&hist[t], 1);
}

// ---------------- z_q gather/write (B,C,H,W) + per-block sq-err partial ----------------
__global__ void zq_kernel(const float* __restrict__ z, const float* __restrict__ emb,
                          const int* __restrict__ token, float* __restrict__ out0,
                          float* __restrict__ partial) {
    __shared__ float ps[4];
    int t = blockIdx.x * 256 + threadIdx.x;
    int w = t & 31, h = (t >> 5) & 31, b = t >> 18;
    int c = (t >> 10) & 255;
    int i = b * 1024 + h * 32 + w;
    int tok = token[i];
    float v = emb[(size_t)tok * C_DIM + c];
    float zv = z[t];
    float d = v - zv;
    out0[t] = v;
    float s = d * d;
#pragma unroll
    for (int m = 32; m >= 1; m >>= 1) s += __shfl_xor(s, m);
    if ((threadIdx.x & 63) == 0) ps[threadIdx.x >> 6] = s;
    __syncthreads();
    if (threadIdx.x == 0) partial[blockIdx.x] = ps[0] + ps[1] + ps[2] + ps[3];
}

// ---------------- per-code embedding update + per-code plog/util (no atomics) -------
__global__ void embed_kernel(const f16* __restrict__ zh, const f16* __restrict__ zld,
                             const float* __restrict__ emb,
                             const float* __restrict__ prob, const int* __restrict__ hist,
                             const unsigned long long* __restrict__ colbest,
                             float* __restrict__ newe, float* __restrict__ newp,
                             float* __restrict__ pl, int* __restrict__ ut) {
    int j = blockIdx.x;
    int tid = threadIdx.x; // 64
    int cnt = hist[j];
    float avg = (float)cnt * (1.0f / 16384.0f);
    float npb = prob[j] * 0.99f + avg * 0.01f;
    float decay = expf(-npb * 8192000.0f - 0.001f);
    if (tid == 0) {
        newp[j] = npb;
        pl[j] = avg * logf(avg + 1e-10f);
        ut[j] = (cnt > 0) ? 1 : 0;
    }
    float4 e4 = *(const float4*)(emb + (size_t)j * C_DIM + tid * 4);
    float4 o = e4;
    if (decay > 0.0f) {
        int far = (int)(colbest[j] & 0xffffffffULL);
        const f16* zhr = zh + (size_t)far * C_DIM + tid * 4;
        const f16* zlr = zld + (size_t)far * C_DIM + tid * 4;
        float om = 1.0f - decay;
        float zq[4];
#pragma unroll
        for (int q = 0; q < 4; q++) zq[q] = (float)zhr[q] + (float)zlr[q];
        o.x = e4.x * om + zq[0] * decay;
        o.y = e4.y * om + zq[1] * decay;
        o.z = e4.z * om + zq[2] * decay;
        o.w = e4.w * om + zq[3] * decay;
    }
    *(float4*)(newe + (size_t)j * C_DIM + tid * 4) = o;
}

// ---------------- scalar finalize: reduce partials, write 4 scalars ----------------
__global__ void final_kernel(const float* __restrict__ partial, const float* __restrict__ pl,
                             const int* __restrict__ ut, float* __restrict__ out) {
    int tid = threadIdx.x;  // 256
    float sq = 0.0f, pg = 0.0f;
    int uc = 0;
    for (int i = tid; i < 16384; i += 256) sq += partial[i];
    for (int i = tid; i < 8192; i += 256) { pg += pl[i]; uc += ut[i]; }
    float ucf = (float)uc;
#pragma unroll
    for (int m = 32; m >= 1; m >>= 1) {
        sq += __shfl_xor(sq, m);
        pg += __shfl_xor(pg, m);
        ucf += __shfl_xor(ucf, m);
    }
    __shared__ float s1[4], s2[4], s3[4];
    if ((tid & 63) == 0) {
        int w = tid >> 6;
        s1[w] = sq; s2[w] = pg; s3[w] = ucf;
    }
    __syncthreads();
    if (tid == 0) {
        float tsq = s1[0] + s1[1] + s1[2] + s1[3];
        float tpg = s2[0] + s2[1] + s2[2] + s2[3];
        float tuc = s3[0] + s3[1] + s3[2] + s3[3];
        out[OUT_LOSS] = 1.25f * tsq / 4194304.0f;
        out[OUT_QERR] = tsq / 16384.0f;
        out[OUT_UTIL] = tuc / 8192.0f;
        out[OUT_PERP] = expf(-tpg);
    }
}

extern "C" void kernel_launch(void* const* d_in, const int* in_sizes, int n_in,
                              void* d_out, int out_size, void* d_ws, size_t ws_size,
                              hipStream_t stream) {
    const float* z = (const float*)d_in[0];
    const float* emb = (const float*)d_in[1];
    const float* prob = (const float*)d_in[2];
    float* out = (float*)d_out;
    float* ws = (float*)d_ws;

    f16* zh = (f16*)(ws + OFF_ZH);
    f16* zld = (f16*)(ws + OFF_ZLD);
    f16* eh = (f16*)(ws + OFF_EH);
    f16* eld = (f16*)(ws + OFF_ELD);
    float* zn = ws + OFF_ZN;
    float* en = ws + OFF_EN;
    unsigned long long* rowbest = (unsigned long long*)(ws + OFF_ROWBEST);
    unsigned long long* colbest = (unsigned long long*)(ws + OFF_COLBEST);
    int* token = (int*)(ws + OFF_TOKEN);
    int* hist = (int*)(ws + OFF_HIST);
    float* part = ws + OFF_PART;
    float* pl = ws + OFF_PL;
    int* ut = (int*)(ws + OFF_UT);

    hipMemsetAsync(rowbest, 0xFF, (N_FEAT + K_CODES) * sizeof(unsigned long long), stream);
    hipMemsetAsync(hist, 0, K_CODES * sizeof(int), stream);

    zprep_kernel<<<dim3(32, 8, 16), dim3(32, 8), 0, stream>>>(z, zh, zld);
    eprep_kernel<<<K_CODES * C_DIM / 4 / 256, 256, 0, stream>>>(emb, eh, eld);
    zn_kernel<<<N_FEAT / 256, 256, 0, stream>>>(z, zn);
    en_kernel<<<K_CODES / 4, 256, 0, stream>>>(emb, en);
    dist_mfma_kernel<<<dim3(K_CODES / 128, N_FEAT / 128), 256, 0, stream>>>(
        zh, zld, eh, eld, zn, en, rowbest, colbest);
    token_kernel<<<N_FEAT / 256, 256, 0, stream>>>(rowbest, token, hist);
    zq_kernel<<<N_FEAT * C_DIM / 256, 256, 0, stream>>>(z, emb, token, out + OUT_ZQ, part);
    embed_kernel<<<K_CODES, 64, 0, stream>>>(zh, zld, emb, prob, hist, colbest,
                                             out + OUT_NEWE, out + OUT_NEWP, pl, ut);
    final_kernel<<<1, 256, 0, stream>>>(part, pl, ut, out);
}

// Round 9
// 508.776 us; speedup vs baseline: 3.0447x; 1.0651x over previous
//
#include <hip/hip_runtime.h>
#include <stdint.h>
#include <math.h>

// Problem constants
#define N_FEAT 16384   // B*H*W = 16*32*32
#define K_CODES 8192
#define C_DIM 256

typedef _Float16 f16;
typedef f16 f16x8 __attribute__((ext_vector_type(8)));
typedef float f32x4 __attribute__((ext_vector_type(4)));

// Workspace layout (float offsets)
#define OFF_ZH      ((size_t)0)            // f16[16384][256]
#define OFF_ZLD     ((size_t)2097152)      // f16[16384][256]  zld = z - zh (unscaled)
#define OFF_EH      ((size_t)4194304)      // f16[8192][256]   eh  = f16(e*16384)
#define OFF_ELD     ((size_t)5242880)      // f16[8192][256]   eld = e*16384 - eh
#define OFF_ZN      ((size_t)6291456)      // f32[16384]
#define OFF_EN      ((size_t)6307840)      // f32[8192]
#define OFF_ROWBEST ((size_t)6316032)      // u64[16384]
#define OFF_COLBEST ((size_t)6348800)      // u64[8192]
#define OFF_TOKEN   ((size_t)6365184)      // int[16384]
#define OFF_HIST    ((size_t)6381568)      // int[8192]
// rowbest region dead after token_kernel -> reuse:
#define OFF_PART    OFF_ROWBEST            // f32[16384]
#define OFF_PL      (OFF_ROWBEST + 16384)  // f32[8192]
#define OFF_UT      (OFF_ROWBEST + 24576)  // int[8192]

// Output layout (float offsets into d_out)
#define OUT_ZQ    ((size_t)0)
#define OUT_LOSS  ((size_t)4194304)
#define OUT_QERR  ((size_t)4194305)
#define OUT_UTIL  ((size_t)4194306)
#define OUT_PERP  ((size_t)4194307)
#define OUT_NEWE  ((size_t)4194308)
#define OUT_NEWP  ((size_t)6291460)

__device__ __forceinline__ unsigned order_f32(float f) {
    unsigned u = __float_as_uint(f);
    return (u & 0x80000000u) ? ~u : (u | 0x80000000u);
}
__device__ __forceinline__ unsigned long long pack_min_key(float f, unsigned idx) {
    return ((unsigned long long)order_f32(f) << 32) | idx;
}
__device__ __forceinline__ unsigned long long pack_max_key(float f, unsigned idx) {
    return ((unsigned long long)(~order_f32(f)) << 32) | idx;
}

// async global->LDS, 16 B per lane (dest: wave-uniform base + lane*16)
__device__ __forceinline__ void gload16(const f16* g, f16* l) {
    __builtin_amdgcn_global_load_lds(
        (const __attribute__((address_space(1))) unsigned int*)(const void*)g,
        (__attribute__((address_space(3))) unsigned int*)(void*)l,
        16, 0, 0);
}

// ---------------- transpose z (B,C,H,W) -> split-f16 zh/zld in (N,C) ----------------
__global__ void zprep_kernel(const float* __restrict__ z, f16* __restrict__ zh,
                             f16* __restrict__ zld) {
    __shared__ float tile[32][33];
    const int b = blockIdx.z;
    const int c0 = blockIdx.y * 32;
    const int hw0 = blockIdx.x * 32;
    const int tx = threadIdx.x, ty = threadIdx.y; // 32 x 8
#pragma unroll
    for (int i = 0; i < 4; i++) {
        int c = c0 + ty + i * 8;
        tile[ty + i * 8][tx] = z[(size_t)(b * 256 + c) * 1024 + hw0 + tx];
    }
    __syncthreads();
#pragma unroll
    for (int i = 0; i < 4; i++) {
        int hw = hw0 + ty + i * 8;
        float v = tile[tx][ty + i * 8];
        f16 h = (f16)v;
        size_t o = (size_t)(b * 1024 + hw) * 256 + c0 + tx;
        zh[o] = h;
        zld[o] = (f16)(v - (float)h);
    }
}

// ---------------- embedding -> split-f16 (scaled by 16384) ----------------
__global__ void eprep_kernel(const float* __restrict__ emb, f16* __restrict__ eh,
                             f16* __restrict__ eld) {
    int i = blockIdx.x * 256 + threadIdx.x;  // per 4 elements
    float4 v = *(const float4*)(emb + (size_t)i * 4);
    float s[4] = {v.x, v.y, v.z, v.w};
    f16 h[4], l[4];
#pragma unroll
    for (int q = 0; q < 4; q++) {
        float es = s[q] * 16384.0f;
        h[q] = (f16)es;
        l[q] = (f16)(es - (float)h[q]);
    }
    *(uint64_t*)(eh + (size_t)i * 4) = *(uint64_t*)h;
    *(uint64_t*)(eld + (size_t)i * 4) = *(uint64_t*)l;
}

// ---------------- zn from z ----------------
__global__ void zn_kernel(const float* __restrict__ z, float* __restrict__ zn) {
    int i = blockIdx.x * 256 + threadIdx.x;
    int b = i >> 10, hw = i & 1023;
    const float* p = z + (size_t)b * 262144 + hw;
    float s = 0.0f;
#pragma unroll 8
    for (int c = 0; c < 256; c++) { float v = p[(size_t)c * 1024]; s = fmaf(v, v, s); }
    zn[i] = s;
}

// ---------------- en from emb rows ----------------
__global__ void en_kernel(const float* __restrict__ emb, float* __restrict__ en) {
    int gid = blockIdx.x * 4 + (threadIdx.x >> 6);
    int lane = threadIdx.x & 63;
    float4 v = *(const float4*)(emb + (size_t)gid * 256 + lane * 4);
    float s = v.x * v.x + v.y * v.y + v.z * v.z + v.w * v.w;
#pragma unroll
    for (int m = 32; m >= 1; m >>= 1) s += __shfl_xor(s, m);
    if (lane == 0) en[gid] = s;
}

// ---------------- MFMA distance + fused argmin/argmax (concat-K, single acc) --------
// 128x128 tile, 4 waves (2x2). K' = 768 in 24 chunks of 32:
//   c<8 : zh  x eh ; 8-15: zld x eh ; 16+: zh x eld
// acc = dot * 16384;  d = zn + en - acc * (2/16384).
// 3-buffer LDS, 2-deep prefetch, counted vmcnt(4) per iter (T4); XCD-swizzled grid (T1).
__launch_bounds__(256, 3)
__global__ void dist_mfma_kernel(const f16* __restrict__ zh, const f16* __restrict__ zld,
                                 const f16* __restrict__ eh, const f16* __restrict__ eld,
                                 const float* __restrict__ zn, const float* __restrict__ en,
                                 unsigned long long* __restrict__ rowbest,
                                 unsigned long long* __restrict__ colbest) {
    __shared__ f16 sA[3][4096];   // 128 rows x 32 halfs, granule-swizzled
    __shared__ f16 sB[3][4096];

    const int tid = threadIdx.x;
    // XCD swizzle: b%8 = XCD. Each XCD owns kb in [x*8, x*8+8): B-panels (1 MB) stay
    // L2-resident; 8 co-XCD consecutive blocks share each A panel.
    const int b = blockIdx.x;
    const int kb = (b & 7) * 8 + ((b >> 3) & 7);
    const int mb = b >> 6;
    const int m0 = mb * 128;
    const int k0 = kb * 128;
    const int wave = tid >> 6, lane = tid & 63;
    const int wr = wave >> 1, wc = wave & 1;
    const int lg = lane >> 4, l15 = lane & 15;

    // staging: granules G0 = tid, G1 = 256+tid; row = G>>2; src slot = (G&3) ^ ((G>>3)&3)
    const int G0 = tid, G1 = 256 + tid;
    const int aoff0 = (m0 + (G0 >> 2)) * 256 + (((G0 & 3) ^ ((G0 >> 3) & 3)) << 3);
    const int aoff1 = (m0 + (G1 >> 2)) * 256 + (((G1 & 3) ^ ((G1 >> 3) & 3)) << 3);
    const int boff0 = (k0 + (G0 >> 2)) * 256 + (((G0 & 3) ^ ((G0 >> 3) & 3)) << 3);
    const int boff1 = (k0 + (G1 >> 2)) * 256 + (((G1 & 3) ^ ((G1 >> 3) & 3)) << 3);

    // fragment read offsets (halfs): logical (row R, slot lg) lives at slot lg ^ ((R>>1)&3)
    int aro[4], bro[4];
#pragma unroll
    for (int t = 0; t < 4; t++) {
        int R = wr * 64 + t * 16 + l15;
        aro[t] = R * 32 + ((lg ^ ((R >> 1) & 3)) << 3);
        int RB = wc * 64 + t * 16 + l15;
        bro[t] = RB * 32 + ((lg ^ ((RB >> 1) & 3)) << 3);
    }

    f32x4 acc[4][4];
#pragma unroll
    for (int i = 0; i < 4; i++)
#pragma unroll
        for (int j = 0; j < 4; j++) acc[i][j] = (f32x4){0.f, 0.f, 0.f, 0.f};

    auto stage = [&](int cn, int nb) {
        int cp = cn >> 3, cc = (cn & 7) * 32;
        const f16* As = (cp == 1) ? zld : zh;
        const f16* Bs = (cp == 2) ? eld : eh;
        gload16(As + aoff0 + cc, &sA[nb][G0 * 8]);
        gload16(As + aoff1 + cc, &sA[nb][G1 * 8]);
        gload16(Bs + boff0 + cc, &sB[nb][G0 * 8]);
        gload16(Bs + boff1 + cc, &sB[nb][G1 * 8]);
    };

    // prologue: stage chunks 0,1 (8 loads in flight); wait for chunk 0 only
    stage(0, 0);
    stage(1, 1);
    asm volatile("s_waitcnt vmcnt(4)" ::: "memory");
    __builtin_amdgcn_s_barrier();
    __builtin_amdgcn_sched_barrier(0);

    for (int c = 0; c < 24; ++c) {
        const int cur = c % 3;
        if (c + 2 < 24) stage(c + 2, (c + 2) % 3);

        f16x8 af[4];
#pragma unroll
        for (int t = 0; t < 4; t++) af[t] = *(const f16x8*)&sA[cur][aro[t]];
#pragma unroll
        for (int j = 0; j < 4; j++) {
            f16x8 bf = *(const f16x8*)&sB[cur][bro[j]];
#pragma unroll
            for (int i = 0; i < 4; i++)
                acc[i][j] = __builtin_amdgcn_mfma_f32_16x16x32_f16(af[i], bf, acc[i][j], 0, 0, 0);
        }

        // next iter reads buf[(c+1)%3]: its stage (issued last iter) must have landed.
        // Leave this iter's 4 loads (chunk c+2) in flight.
        if (c < 22) asm volatile("s_waitcnt vmcnt(4)" ::: "memory");
        else        asm volatile("s_waitcnt vmcnt(0)" ::: "memory");
        __builtin_amdgcn_s_barrier();
        __builtin_amdgcn_sched_barrier(0);
    }

    // ---- epilogue: d[i][j] = zn[m] + en[k] - acc * 2/16384 ----
    const float sc = 2.0f / 16384.0f;
    float enl[4], znl[4][4];
#pragma unroll
    for (int j = 0; j < 4; j++) enl[j] = en[k0 + wc * 64 + j * 16 + l15];
#pragma unroll
    for (int i = 0; i < 4; i++)
#pragma unroll
        for (int r = 0; r < 4; r++) znl[i][r] = zn[m0 + wr * 64 + i * 16 + lg * 4 + r];

    // per-row argmin over this block's 128 cols (wave covers 64 cols)
#pragma unroll
    for (int i = 0; i < 4; i++)
#pragma unroll
        for (int r = 0; r < 4; r++) {
            float bv = 3.0e38f;
            int bk = 0;
#pragma unroll
            for (int j = 0; j < 4; j++) {
                float d = znl[i][r] + enl[j] - acc[i][j][r] * sc;
                int k = k0 + wc * 64 + j * 16 + l15;
                if (d < bv || (d == bv && k < bk)) { bv = d; bk = k; }
            }
#pragma unroll
            for (int m = 1; m < 16; m <<= 1) {
                float ov = __shfl_xor(bv, m);
                int oi = __shfl_xor(bk, m);
                if (ov < bv || (ov == bv && oi < bk)) { bv = ov; bk = oi; }
            }
            if (l15 == 0)
                atomicMin(&rowbest[m0 + wr * 64 + i * 16 + lg * 4 + r],
                          pack_min_key(bv, (unsigned)bk));
        }

    // per-col argmax over this block's 128 rows (wave covers 64 rows)
#pragma unroll
    for (int j = 0; j < 4; j++) {
        float cv = -3.0e38f;
        int cm = 0;
#pragma unroll
        for (int i = 0; i < 4; i++)
#pragma unroll
            for (int r = 0; r < 4; r++) {
                float d = znl[i][r] + enl[j] - acc[i][j][r] * sc;
                int mm = m0 + wr * 64 + i * 16 + lg * 4 + r;
                if (d > cv || (d == cv && mm < cm)) { cv = d; cm = mm; }
            }
#pragma unroll
        for (int m = 16; m < 64; m <<= 1) {
            float ov = __shfl_xor(cv, m);
            int oi = __shfl_xor(cm, m);
            if (ov > cv || (ov == cv && oi < cm)) { cv = ov; cm = oi; }
        }
        if (lane < 16)
            atomicMin(&colbest[k0 + wc * 64 + j * 16 + l15], pack_max_key(cv, (unsigned)cm));
    }
}

// ---------------- token decode + histogram ----------------
__global__ void token_kernel(const unsigned long long* __restrict__ rowbest,
                             int* __restrict__ token, int* __restrict__ hist) {
    int i = blockIdx.x * 256 + threadIdx.x;
    int t = (int)(rowbest[i] & 0xffffffffULL);
    token[i] = t;
    atomicAdd(&hist[t], 1);
}

// ---------------- z_q gather/write (B,C,H,W) + per-block sq-err partial ----------------
__global__ void zq_kernel(const float* __restrict__ z, const float* __restrict__ emb,
                          const int* __restrict__ token, float* __restrict__ out0,
                          float* __restrict__ partial) {
    __shared__ float ps[4];
    int t = blockIdx.x * 256 + threadIdx.x;
    int w = t & 31, h = (t >> 5) & 31, b = t >> 18;
    int c = (t >> 10) & 255;
    int i = b * 1024 + h * 32 + w;
    int tok = token[i];
    float v = emb[(size_t)tok * C_DIM + c];
    float zv = z[t];
    float d = v - zv;
    out0[t] = v;
    float s = d * d;
#pragma unroll
    for (int m = 32; m >= 1; m >>= 1) s += __shfl_xor(s, m);
    if ((threadIdx.x & 63) == 0) ps[threadIdx.x >> 6] = s;
    __syncthreads();
    if (threadIdx.x == 0) partial[blockIdx.x] = ps[0] + ps[1] + ps[2] + ps[3];
}

// ---------------- per-code embedding update + per-code plog/util (no atomics) -------
__global__ void embed_kernel(const f16* __restrict__ zh, const f16* __restrict__ zld,
                             const float* __restrict__ emb,
                             const float* __restrict__ prob, const int* __restrict__ hist,
                             const unsigned long long* __restrict__ colbest,
                             float* __restrict__ newe, float* __restrict__ newp,
                             float* __restrict__ pl, int* __restrict__ ut) {
    int j = blockIdx.x;
    int tid = threadIdx.x; // 64
    int cnt = hist[j];
    float avg = (float)cnt * (1.0f / 16384.0f);
    float npb = prob[j] * 0.99f + avg * 0.01f;
    float decay = expf(-npb * 8192000.0f - 0.001f);
    if (tid == 0) {
        newp[j] = npb;
        pl[j] = avg * logf(avg + 1e-10f);
        ut[j] = (cnt > 0) ? 1 : 0;
    }
    float4 e4 = *(const float4*)(emb + (size_t)j * C_DIM + tid * 4);
    float4 o = e4;
    if (decay > 0.0f) {
        int far = (int)(colbest[j] & 0xffffffffULL);
        const f16* zhr = zh + (size_t)far * C_DIM + tid * 4;
        const f16* zlr = zld + (size_t)far * C_DIM + tid * 4;
        float om = 1.0f - decay;
        float zq[4];
#pragma unroll
        for (int q = 0; q < 4; q++) zq[q] = (float)zhr[q] + (float)zlr[q];
        o.x = e4.x * om + zq[0] * decay;
        o.y = e4.y * om + zq[1] * decay;
        o.z = e4.z * om + zq[2] * decay;
        o.w = e4.w * om + zq[3] * decay;
    }
    *(float4*)(newe + (size_t)j * C_DIM + tid * 4) = o;
}

// ---------------- scalar finalize: reduce partials, write 4 scalars ----------------
__global__ void final_kernel(const float* __restrict__ partial, const float* __restrict__ pl,
                             const int* __restrict__ ut, float* __restrict__ out) {
    int tid = threadIdx.x;  // 256
    float sq = 0.0f, pg = 0.0f;
    int uc = 0;
    for (int i = tid; i < 16384; i += 256) sq += partial[i];
    for (int i = tid; i < 8192; i += 256) { pg += pl[i]; uc += ut[i]; }
    float ucf = (float)uc;
#pragma unroll
    for (int m = 32; m >= 1; m >>= 1) {
        sq += __shfl_xor(sq, m);
        pg += __shfl_xor(pg, m);
        ucf += __shfl_xor(ucf, m);
    }
    __shared__ float s1[4], s2[4], s3[4];
    if ((tid & 63) == 0) {
        int w = tid >> 6;
        s1[w] = sq; s2[w] = pg; s3[w] = ucf;
    }
    __syncthreads();
    if (tid == 0) {
        float tsq = s1[0] + s1[1] + s1[2] + s1[3];
        float tpg = s2[0] + s2[1] + s2[2] + s2[3];
        float tuc = s3[0] + s3[1] + s3[2] + s3[3];
        out[OUT_LOSS] = 1.25f * tsq / 4194304.0f;
        out[OUT_QERR] = tsq / 16384.0f;
        out[OUT_UTIL] = tuc / 8192.0f;
        out[OUT_PERP] = expf(-tpg);
    }
}

extern "C" void kernel_launch(void* const* d_in, const int* in_sizes, int n_in,
                              void* d_out, int out_size, void* d_ws, size_t ws_size,
                              hipStream_t stream) {
    const float* z = (const float*)d_in[0];
    const float* emb = (const float*)d_in[1];
    const float* prob = (const float*)d_in[2];
    float* out = (float*)d_out;
    float* ws = (float*)d_ws;

    f16* zh = (f16*)(ws + OFF_ZH);
    f16* zld = (f16*)(ws + OFF_ZLD);
    f16* eh = (f16*)(ws + OFF_EH);
    f16* eld = (f16*)(ws + OFF_ELD);
    float* zn = ws + OFF_ZN;
    float* en = ws + OFF_EN;
    unsigned long long* rowbest = (unsigned long long*)(ws + OFF_ROWBEST);
    unsigned long long* colbest = (unsigned long long*)(ws + OFF_COLBEST);
    int* token = (int*)(ws + OFF_TOKEN);
    int* hist = (int*)(ws + OFF_HIST);
    float* part = ws + OFF_PART;
    float* pl = ws + OFF_PL;
    int* ut = (int*)(ws + OFF_UT);

    hipMemsetAsync(rowbest, 0xFF, (N_FEAT + K_CODES) * sizeof(unsigned long long), stream);
    hipMemsetAsync(hist, 0, K_CODES * sizeof(int), stream);

    zprep_kernel<<<dim3(32, 8, 16), dim3(32, 8), 0, stream>>>(z, zh, zld);
    eprep_kernel<<<K_CODES * C_DIM / 4 / 256, 256, 0, stream>>>(emb, eh, eld);
    zn_kernel<<<N_FEAT / 256, 256, 0, stream>>>(z, zn);
    en_kernel<<<K_CODES / 4, 256, 0, stream>>>(emb, en);
    dist_mfma_kernel<<<dim3(8192), 256, 0, stream>>>(
        zh, zld, eh, eld, zn, en, rowbest, colbest);
    token_kernel<<<N_FEAT / 256, 256, 0, stream>>>(rowbest, token, hist);
    zq_kernel<<<N_FEAT * C_DIM / 256, 256, 0, stream>>>(z, emb, token, out + OUT_ZQ, part);
    embed_kernel<<<K_CODES, 64, 0, stream>>>(zh, zld, emb, prob, hist, colbest,
                                             out + OUT_NEWE, out + OUT_NEWP, pl, ut);
    final_kernel<<<1, 256, 0, stream>>>(part, pl, ut, out);
}